// Round 1
// baseline (731.424 us; speedup 1.0000x reference)
//
#include <hip/hip_runtime.h>
#include <math.h>

// Raymarcher: per-ray LSTM refinement, fp32 VALU implementation.
// One thread = one ray. Weights packed f-major in d_ws so uniform (scalar)
// loads feed the 64-gate FMA inner loop.

#define FEAT 256
#define HID  16
#define GATES 64
#define STEPS 10

// packed layout (floats):
//   [f*68 + 0..2]  = W_phi[0..2][f]
//   [f*68 + 3]     = b_phi[f]
//   [f*68 + 4+g]   = W_ih[g][f]          (f = 0..255)
//   [17408 + g]    = b_ih[g] + b_hh[g]
//   [17472 + g*16+j] = W_hh[g][j]
//   [18496 + j]    = W_out[j]
//   [18512]        = b_out
#define OFF_GB   17408
#define OFF_WHH  17472
#define OFF_WOUT 18496
#define OFF_BOUT 18512
#define PACK_FLOATS 18513

__global__ void prep_pack(const float* __restrict__ Wphi, const float* __restrict__ bphi,
                          const float* __restrict__ Wih,  const float* __restrict__ bih,
                          const float* __restrict__ Whh,  const float* __restrict__ bhh,
                          const float* __restrict__ Wout, const float* __restrict__ bout,
                          float* __restrict__ ws) {
    int f = threadIdx.x;  // 256 threads
    float* blk = ws + f * 68;
    blk[0] = Wphi[f];
    blk[1] = Wphi[FEAT + f];
    blk[2] = Wphi[2 * FEAT + f];
    blk[3] = bphi[f];
    for (int g = 0; g < GATES; ++g) blk[4 + g] = Wih[g * FEAT + f];
    if (f < GATES) {
        ws[OFF_GB + f] = bih[f] + bhh[f];
        for (int j = 0; j < HID; ++j) ws[OFF_WHH + f * HID + j] = Whh[f * HID + j];
    }
    if (f == 0) {
        for (int j = 0; j < HID; ++j) ws[OFF_WOUT + j] = Wout[j];
        ws[OFF_BOUT] = bout[0];
    }
}

__device__ __forceinline__ float sigf(float x) {
    x = fminf(30.f, fmaxf(-30.f, x));
    return __fdividef(1.f, 1.f + __expf(-x));
}
__device__ __forceinline__ float tanhf_fast(float x) {
    x = fminf(15.f, fmaxf(-15.f, x));
    float e = __expf(2.f * x);
    return __fdividef(e - 1.f, e + 1.f);
}

template <bool PACKED>
__global__ __launch_bounds__(256, 2) void raymarch(
    const float* __restrict__ c2w, const float* __restrict__ intr,
    const float* __restrict__ uv,  const float* __restrict__ dep0,
    const float* __restrict__ pack,
    const float* __restrict__ Wphi, const float* __restrict__ bphi,
    const float* __restrict__ Wih,  const float* __restrict__ bih,
    const float* __restrict__ Whh,  const float* __restrict__ bhh,
    const float* __restrict__ Wout, const float* __restrict__ bout,
    float* __restrict__ out, int B, int N) {
    int ray = blockIdx.x * blockDim.x + threadIdx.x;
    int BN = B * N;
    if (ray >= BN) return;
    int b = ray / N;

    const float* M = c2w + b * 16;
    float R00 = M[0], R01 = M[1], R02 = M[2], t0 = M[3];
    float R10 = M[4], R11 = M[5], R12 = M[6], t1 = M[7];
    float R20 = M[8], R21 = M[9], R22 = M[10], t2 = M[11];
    const float* Kc = intr + b * 9;
    float fx = Kc[0], cx = Kc[2], fy = Kc[4], cy = Kc[5];

    float u = uv[ray * 2 + 0];
    float v = uv[ray * 2 + 1];
    float d0 = dep0[ray];

    float xl = (u - cx) / fx;
    float yl = (v - cy) / fy;
    // unnormalized dir = R @ [xl, yl, 1]
    float dx = R00 * xl + R01 * yl + R02;
    float dy = R10 * xl + R11 * yl + R12;
    float dz = R20 * xl + R21 * yl + R22;
    float invn = rsqrtf(dx * dx + dy * dy + dz * dz);
    float rdx = dx * invn, rdy = dy * invn, rdz = dz * invn;
    // world0 = d0 * dir + t
    float w0 = fmaf(dx, d0, t0);
    float w1 = fmaf(dy, d0, t1);
    float w2 = fmaf(dz, d0, t2);

    float h[HID], c[HID];
#pragma unroll
    for (int j = 0; j < HID; ++j) { h[j] = 0.f; c[j] = 0.f; }

    const float* gbp   = PACKED ? (pack + OFF_GB)   : nullptr;
    const float* whhp  = PACKED ? (pack + OFF_WHH)  : Whh;
    const float* woutp = PACKED ? (pack + OFF_WOUT) : Wout;
    float bo           = PACKED ? pack[OFF_BOUT]    : bout[0];

#pragma unroll 1
    for (int s = 0; s < STEPS; ++s) {
        float gates[GATES];
#pragma unroll
        for (int g = 0; g < GATES; ++g) {
            float acc = PACKED ? gbp[g] : (bih[g] + bhh[g]);
#pragma unroll
            for (int j = 0; j < HID; ++j) acc = fmaf(h[j], whhp[g * HID + j], acc);
            gates[g] = acc;
        }

#pragma unroll 2
        for (int f = 0; f < FEAT; ++f) {
            const float* blk = PACKED ? (pack + f * 68) : nullptr;
            float p0 = PACKED ? blk[0] : Wphi[f];
            float p1 = PACKED ? blk[1] : Wphi[FEAT + f];
            float p2 = PACKED ? blk[2] : Wphi[2 * FEAT + f];
            float p3 = PACKED ? blk[3] : bphi[f];
            float a = fmaf(w0, p0, fmaf(w1, p1, fmaf(w2, p2, p3)));
            float vf = fmaxf(a, 0.f);
            if (__any(vf > 0.f)) {
#pragma unroll
                for (int g = 0; g < GATES; ++g) {
                    float wg = PACKED ? blk[4 + g] : Wih[g * FEAT + f];
                    gates[g] = fmaf(vf, wg, gates[g]);
                }
            }
        }

        float sd = bo;
#pragma unroll
        for (int j = 0; j < HID; ++j) {
            float ig = sigf(gates[j]);
            float fg = sigf(gates[HID + j]);
            float gg = tanhf_fast(gates[2 * HID + j]);
            float og = sigf(gates[3 * HID + j]);
            float cn = fmaf(fg, c[j], ig * gg);
            c[j] = cn;
            float hn = og * tanhf_fast(cn);
            h[j] = hn;
            sd = fmaf(hn, woutp[j], sd);
        }
        w0 = fmaf(rdx, sd, w0);
        w1 = fmaf(rdy, sd, w1);
        w2 = fmaf(rdz, sd, w2);
    }

    int base = ray * 3;
    out[base + 0] = w0;
    out[base + 1] = w1;
    out[base + 2] = w2;
    // depth = (R^T (world - t))[2]  (rigid inverse of cam2world)
    float dd = R02 * (w0 - t0) + R12 * (w1 - t1) + R22 * (w2 - t2);
    out[BN * 3 + ray] = dd;
}

extern "C" void kernel_launch(void* const* d_in, const int* in_sizes, int n_in,
                              void* d_out, int out_size, void* d_ws, size_t ws_size,
                              hipStream_t stream) {
    const float* c2w  = (const float*)d_in[0];
    const float* intr = (const float*)d_in[1];
    const float* uv   = (const float*)d_in[2];
    const float* dep  = (const float*)d_in[3];
    const float* Wphi = (const float*)d_in[4];
    const float* bphi = (const float*)d_in[5];
    const float* Wih  = (const float*)d_in[6];
    const float* bih  = (const float*)d_in[7];
    const float* Whh  = (const float*)d_in[8];
    const float* bhh  = (const float*)d_in[9];
    const float* Wout = (const float*)d_in[10];
    const float* bout = (const float*)d_in[11];
    float* out = (float*)d_out;

    int B = in_sizes[0] / 16;   // cam2world B*4*4
    int BN = in_sizes[3];       // initial_depth B*N
    int N = BN / B;
    int blocks = (BN + 255) / 256;

    bool packed = (ws_size >= PACK_FLOATS * sizeof(float));
    if (packed) {
        prep_pack<<<1, 256, 0, stream>>>(Wphi, bphi, Wih, bih, Whh, bhh, Wout, bout,
                                         (float*)d_ws);
        raymarch<true><<<blocks, 256, 0, stream>>>(
            c2w, intr, uv, dep, (const float*)d_ws,
            Wphi, bphi, Wih, bih, Whh, bhh, Wout, bout, out, B, N);
    } else {
        raymarch<false><<<blocks, 256, 0, stream>>>(
            c2w, intr, uv, dep, nullptr,
            Wphi, bphi, Wih, bih, Whh, bhh, Wout, bout, out, B, N);
    }
}

// Round 2
// 240.249 us; speedup vs baseline: 3.0444x; 3.0444x over previous
//
#include <hip/hip_runtime.h>
#include <math.h>

#define FEAT 256
#define HID  16
#define GATES 64
#define STEPS 10
#define KCH 9   // 8 feature chunks of K=32 + 1 chunk holding [h | 1 | 0] (recurrence+bias)

// d_ws layout (written by prep kernel every launch):
//   [0, 36864)        : B-pack, bf16 ushort[KCH][4][64][8]  (MFMA B-fragment order)
//   [36864, 40960)    : phi pack, float[256][4] = {Wphi0,Wphi1,Wphi2,bphi}
#define WS_BPACK_N   (KCH*4*64*8)
#define WS_PHI_OFF_B 36864
#define WS_TOTAL_B   (36864 + 4096)

typedef unsigned short ushort_t;
typedef unsigned int uint_t;
typedef __attribute__((ext_vector_type(8))) short short8;
typedef __attribute__((ext_vector_type(4))) float floatx4;
typedef __attribute__((ext_vector_type(4))) unsigned int uintx4;

__device__ __host__ __forceinline__ ushort_t f2bf_bits(float f) {
    union { float f; unsigned u; } cv; cv.f = f;
    unsigned u = cv.u;
    u = (u + 0x7FFFu + ((u >> 16) & 1u)) >> 16;   // RNE
    return (ushort_t)u;
}

__device__ __forceinline__ unsigned pk2bf(float lo, float hi) {
    unsigned r;
    asm("v_cvt_pk_bf16_f32 %0, %1, %2" : "=v"(r) : "v"(lo), "v"(hi));
    return r;
}

__device__ __forceinline__ float sigf(float x) {
    x = fminf(30.f, fmaxf(-30.f, x));
    return __fdividef(1.f, 1.f + __expf(-x));
}
__device__ __forceinline__ float tanhf_fast(float x) {
    x = fminf(15.f, fmaxf(-15.f, x));
    float e = __expf(2.f * x);
    return __fdividef(e - 1.f, e + 1.f);
}

// ---------------- prep: pack weights into MFMA fragment order ----------------
__global__ void prep(const float* __restrict__ Wphi, const float* __restrict__ bphi,
                     const float* __restrict__ Wih,  const float* __restrict__ bih,
                     const float* __restrict__ Whh,  const float* __restrict__ bhh,
                     void* __restrict__ ws) {
    int tid = threadIdx.x;  // 256
    ushort_t* bp = (ushort_t*)ws;
    // B fragment: lane l holds B[k = kc*32 + (l>>4)*8 + e][col = n*16 + (l&15)]
    for (int idx = tid; idx < WS_BPACK_N; idx += 256) {
        int e    = idx & 7;
        int lane = (idx >> 3) & 63;
        int n    = (idx >> 9) & 3;
        int kc   = idx >> 11;
        int k    = kc * 32 + (lane >> 4) * 8 + e;
        int col  = n * 16 + (lane & 15);
        float v;
        if (k < FEAT) {
            v = Wih[col * FEAT + k];
        } else {
            int k16 = k - FEAT;
            if (k16 < HID)       v = Whh[col * HID + k16];
            else if (k16 == HID) v = bih[col] + bhh[col];
            else                 v = 0.f;
        }
        bp[idx] = f2bf_bits(v);
    }
    float* pp = (float*)((char*)ws + WS_PHI_OFF_B);
    int f = tid;
    pp[f * 4 + 0] = Wphi[f];
    pp[f * 4 + 1] = Wphi[FEAT + f];
    pp[f * 4 + 2] = Wphi[2 * FEAT + f];
    pp[f * 4 + 3] = bphi[f];
}

// ---------------- main kernel ----------------
__global__ __launch_bounds__(256, 2) void march(
    const float* __restrict__ c2w, const float* __restrict__ intr,
    const float* __restrict__ uv,  const float* __restrict__ dep0,
    const void* __restrict__ ws,   const float* __restrict__ Wout,
    const float* __restrict__ bout, float* __restrict__ out, int B, int N) {

    // per-block LDS: 36864 + 20480 + 20480 + 1024 = 78848 B -> 2 blocks/CU
    __shared__ __align__(16) ushort_t Blds[WS_BPACK_N];   // W fragments (shared)
    __shared__ __align__(16) ushort_t Xlds[4][64][40];    // per-wave X chunk, 80B rows
    __shared__ __align__(16) ushort_t Hlds[4][64][40];    // per-wave [h | 1 | 0] chunk
    __shared__ __align__(16) float    Sdls[4][64];        // per-wave sd broadcast

    int tid = threadIdx.x;
    int w = tid >> 6, l = tid & 63;
    int lc = l & 15, lg = l >> 4;
    int ray = blockIdx.x * 256 + tid;
    int BN = B * N;
    int b = ray / N;  // uniform per block (N % 256 == 0)

    // stage B-pack into LDS (shared by the 4 waves)
    {
        const uintx4* src = (const uintx4*)ws;
        uintx4* dst = (uintx4*)Blds;
        for (int i = tid; i < WS_BPACK_N / 8; i += 256) dst[i] = src[i];
    }

    const float* M = c2w + b * 16;
    float R00 = M[0], R01 = M[1], R02 = M[2], t0 = M[3];
    float R10 = M[4], R11 = M[5], R12 = M[6], t1 = M[7];
    float R20 = M[8], R21 = M[9], R22 = M[10], t2 = M[11];
    const float* Kc = intr + b * 9;
    float fx = Kc[0], cx = Kc[2], fy = Kc[4], cy = Kc[5];

    float u = uv[ray * 2 + 0];
    float v = uv[ray * 2 + 1];
    float d0 = dep0[ray];

    float xl = (u - cx) / fx;
    float yl = (v - cy) / fy;
    float dx = R00 * xl + R01 * yl + R02;
    float dy = R10 * xl + R11 * yl + R12;
    float dz = R20 * xl + R21 * yl + R22;
    float invn = rsqrtf(dx * dx + dy * dy + dz * dz);
    float rdx = dx * invn, rdy = dy * invn, rdz = dz * invn;
    float w0 = fmaf(dx, d0, t0);
    float w1 = fmaf(dy, d0, t1);
    float w2 = fmaf(dz, d0, t2);

    // init Hlds: cols 0-15 (h) = 0, col 16 = 1.0 (bias), 17-31 = 0
    {
        uintx4 z4 = {0u, 0u, 0u, 0u};
        uintx4 o4 = {0x00003F80u, 0u, 0u, 0u};
        uintx4* hr = (uintx4*)&Hlds[w][l][0];
        hr[0] = z4; hr[1] = z4; hr[2] = o4; hr[3] = z4;
    }

    float wj = Wout[lc];
    float bo = bout[0];

    float h[HID], c[HID];
#pragma unroll
    for (int j = 0; j < HID; ++j) { h[j] = 0.f; c[j] = 0.f; }

    const floatx4* phip = (const floatx4*)((const char*)ws + WS_PHI_OFF_B);

    __syncthreads();  // Blds staged

#pragma unroll 1
    for (int s = 0; s < STEPS; ++s) {
        floatx4 acc[4][4];
#pragma unroll
        for (int m = 0; m < 4; ++m)
#pragma unroll
            for (int n = 0; n < 4; ++n) acc[m][n] = (floatx4){0.f, 0.f, 0.f, 0.f};

        // chunks 0..7: vf features through LDS transpose into MFMA
#pragma unroll 1
        for (int kc = 0; kc < 8; ++kc) {
            unsigned vp[16];
#pragma unroll
            for (int t = 0; t < 32; t += 2) {
                floatx4 p0 = phip[kc * 32 + t];
                floatx4 p1 = phip[kc * 32 + t + 1];
                float a0 = fmaf(w0, p0.x, fmaf(w1, p0.y, fmaf(w2, p0.z, p0.w)));
                float a1 = fmaf(w0, p1.x, fmaf(w1, p1.y, fmaf(w2, p1.z, p1.w)));
                vp[t >> 1] = pk2bf(fmaxf(a0, 0.f), fmaxf(a1, 0.f));
            }
            {
                uintx4* xr = (uintx4*)&Xlds[w][l][0];
                const uintx4* vv = (const uintx4*)vp;
                xr[0] = vv[0]; xr[1] = vv[1]; xr[2] = vv[2]; xr[3] = vv[3];
            }
            short8 af[4], bf[4];
#pragma unroll
            for (int m = 0; m < 4; ++m)
                af[m] = *(const short8*)&Xlds[w][16 * m + lc][lg * 8];
#pragma unroll
            for (int n = 0; n < 4; ++n)
                bf[n] = *(const short8*)&Blds[((kc * 4 + n) * 64 + l) * 8];
#pragma unroll
            for (int m = 0; m < 4; ++m)
#pragma unroll
                for (int n = 0; n < 4; ++n)
                    acc[m][n] = __builtin_amdgcn_mfma_f32_16x16x32_bf16(
                        af[m], bf[n], acc[m][n], 0, 0, 0);
        }

        // chunk 8: [h | 1 | 0] @ [Whh^T; bias; 0]  (recurrence + biases)
        {
            short8 af[4], bf[4];
#pragma unroll
            for (int m = 0; m < 4; ++m)
                af[m] = *(const short8*)&Hlds[w][16 * m + lc][lg * 8];
#pragma unroll
            for (int n = 0; n < 4; ++n)
                bf[n] = *(const short8*)&Blds[((8 * 4 + n) * 64 + l) * 8];
#pragma unroll
            for (int m = 0; m < 4; ++m)
#pragma unroll
                for (int n = 0; n < 4; ++n)
                    acc[m][n] = __builtin_amdgcn_mfma_f32_16x16x32_bf16(
                        af[m], bf[n], acc[m][n], 0, 0, 0);
        }

        // LSTM in C/D layout: lane holds rays {16m + 4*lg + i}, hidden j = lc.
        // col-tile n: 0=i,1=f,2=g,3=o
        float sp[4][4];
#pragma unroll
        for (int m = 0; m < 4; ++m) {
#pragma unroll
            for (int i = 0; i < 4; ++i) {
                float ig = sigf(acc[m][0][i]);
                float fg = sigf(acc[m][1][i]);
                float gg = tanhf_fast(acc[m][2][i]);
                float og = sigf(acc[m][3][i]);
                int idx = m * 4 + i;
                float cn = fmaf(fg, c[idx], ig * gg);
                c[idx] = cn;
                float hn = og * tanhf_fast(cn);
                h[idx] = hn;
                sp[m][i] = hn * wj;
            }
        }
        // reduce sd over the 16 lanes (hidden dims) sharing the same rays
#pragma unroll
        for (int r = 1; r < 16; r <<= 1) {
#pragma unroll
            for (int m = 0; m < 4; ++m)
#pragma unroll
                for (int i = 0; i < 4; ++i)
                    sp[m][i] += __shfl_xor(sp[m][i], r, 64);
        }
        if (lc == 0) {
#pragma unroll
            for (int m = 0; m < 4; ++m) {
                floatx4 vv = {sp[m][0], sp[m][1], sp[m][2], sp[m][3]};
                *(floatx4*)&Sdls[w][16 * m + 4 * lg] = vv;
            }
        }
        // write h (bf16) into Hlds for next step's chunk 8
#pragma unroll
        for (int m = 0; m < 4; ++m)
#pragma unroll
            for (int i = 0; i < 4; ++i)
                Hlds[w][16 * m + 4 * lg + i][lc] = f2bf_bits(h[m * 4 + i]);

        float sdv = Sdls[w][l] + bo;
        w0 = fmaf(rdx, sdv, w0);
        w1 = fmaf(rdy, sdv, w1);
        w2 = fmaf(rdz, sdv, w2);
    }

    int base = ray * 3;
    out[base + 0] = w0;
    out[base + 1] = w1;
    out[base + 2] = w2;
    float dd = R02 * (w0 - t0) + R12 * (w1 - t1) + R22 * (w2 - t2);
    out[BN * 3 + ray] = dd;
}

extern "C" void kernel_launch(void* const* d_in, const int* in_sizes, int n_in,
                              void* d_out, int out_size, void* d_ws, size_t ws_size,
                              hipStream_t stream) {
    const float* c2w  = (const float*)d_in[0];
    const float* intr = (const float*)d_in[1];
    const float* uv   = (const float*)d_in[2];
    const float* dep  = (const float*)d_in[3];
    const float* Wphi = (const float*)d_in[4];
    const float* bphi = (const float*)d_in[5];
    const float* Wih  = (const float*)d_in[6];
    const float* bih  = (const float*)d_in[7];
    const float* Whh  = (const float*)d_in[8];
    const float* bhh  = (const float*)d_in[9];
    const float* Wout = (const float*)d_in[10];
    const float* bout = (const float*)d_in[11];
    float* out = (float*)d_out;

    int B = in_sizes[0] / 16;
    int BN = in_sizes[3];
    int N = BN / B;
    int blocks = (BN + 255) / 256;

    prep<<<1, 256, 0, stream>>>(Wphi, bphi, Wih, bih, Whh, bhh, d_ws);
    march<<<blocks, 256, 0, stream>>>(c2w, intr, uv, dep, d_ws, Wout, bout, out, B, N);
}

// Round 5
// 159.306 us; speedup vs baseline: 4.5913x; 1.5081x over previous
//
#include <hip/hip_runtime.h>
#include <math.h>

#define FEAT 256
#define HID  16
#define GATES 64
#define STEPS 10

// d_ws layout (bytes):
//   [0, 36864)        : gates B-pack, bf16 ushort[9][4][64][8]  (16x16x32 B-frag order, pre-scaled by log2e / 2log2e)
//   [36864, 45056)    : phi A-pack,  bf16 ushort[8][64][8]      (32x32x16 A-frag order)
#define GPACK_N   (9*4*64*8)
#define PHIA_N    (8*64*8)
#define WS_PHIA_B 36864

typedef unsigned short ushort_t;
typedef __attribute__((ext_vector_type(8)))  short  short8;
typedef __attribute__((ext_vector_type(4)))  float  floatx4;
typedef __attribute__((ext_vector_type(16))) float  floatx16;
typedef __attribute__((ext_vector_type(2)))  unsigned int uint2v;
typedef __attribute__((ext_vector_type(4)))  unsigned int uintx4;

__device__ __forceinline__ ushort_t f2bf_bits(float f) {
    union { float f; unsigned u; } cv; cv.f = f;
    unsigned u = cv.u;
    u = (u + 0x7FFFu + ((u >> 16) & 1u)) >> 16;   // RNE
    return (ushort_t)u;
}

__device__ __forceinline__ unsigned pk2bf(float lo, float hi) {
    unsigned r;
    asm("v_cvt_pk_bf16_f32 %0, %1, %2" : "=v"(r) : "v"(lo), "v"(hi));
    return r;
}

// relu two f32 then pack to bf16 pair (v_max_f32 x2 + v_cvt_pk_bf16_f32)
__device__ __forceinline__ unsigned relupk(float a, float b) {
    return pk2bf(fmaxf(a, 0.f), fmaxf(b, 0.f));
}

// split f32 into (hi_bf16, lo_bf16) packed dword: hi = truncate, lo = RNE(residual)
__device__ __forceinline__ unsigned packhl(float x) {
    unsigned u = __float_as_uint(x);
    float hi = __uint_as_float(u & 0xFFFF0000u);
    return pk2bf(hi, x - hi);
}

// ---------------- prep: pack weights into MFMA fragment order (parallel) ----------------
__global__ void prep(const float* __restrict__ Wphi, const float* __restrict__ bphi,
                     const float* __restrict__ Wih,  const float* __restrict__ bih,
                     const float* __restrict__ Whh,  const float* __restrict__ bhh,
                     void* __restrict__ ws) {
    int idx = blockIdx.x * 256 + threadIdx.x;
    const float L = 1.4426950408889634f;  // log2(e)
    if (idx < GPACK_N) {
        // gates B-frag (16x16x32): lane l holds B[k = kc*32 + (l>>4)*8 + e][col = n*16 + (l&15)]
        int e    = idx & 7;
        int lane = (idx >> 3) & 63;
        int n    = (idx >> 9) & 3;
        int kc   = idx >> 11;
        int k    = kc * 32 + (lane >> 4) * 8 + e;
        int col  = n * 16 + (lane & 15);
        float v;
        if (k < FEAT) {
            v = Wih[col * FEAT + k];
        } else {
            int k2 = k - FEAT;
            if (k2 < HID)       v = Whh[col * HID + k2];
            else if (k2 == HID) v = bih[col] + bhh[col];
            else                v = 0.f;
        }
        float sc = (col >= 32 && col < 48) ? (2.f * L) : L;  // g-gate gets 2*log2e (tanh)
        ((ushort_t*)ws)[idx] = f2bf_bits(v * sc);
    } else if (idx < GPACK_N + PHIA_N) {
        // phi A-frag (32x32x16): lane l holds A[row = ft*32 + (l&31)][k = (l>>5)*8 + e]
        // k entries multiply [w0h,w0l,w1h,w1l,w2h,w2l,1,0]; lanes >=32 are k=8..15 (zero)
        int j    = idx - GPACK_N;
        int e    = j & 7;
        int lane = (j >> 3) & 63;
        int ft   = j >> 9;
        int f    = ft * 32 + (lane & 31);
        float v = 0.f;
        if (lane < 32) {
            if (e < 6)       v = Wphi[(e >> 1) * FEAT + f];
            else if (e == 6) v = bphi[f];
        }
        ((ushort_t*)((char*)ws + WS_PHIA_B))[j] = f2bf_bits(v);
    }
}

// ---------------- main kernel ----------------
__global__ __launch_bounds__(256, 2) void march(
    const float* __restrict__ c2w, const float* __restrict__ intr,
    const float* __restrict__ uv,  const float* __restrict__ dep0,
    const void* __restrict__ ws,   const float* __restrict__ Wout,
    const float* __restrict__ bout, float* __restrict__ out, int B, int N) {

    __shared__ __align__(16) ushort_t Blds[GPACK_N];      // gate W fragments (all 9 chunks)
    __shared__ __align__(16) ushort_t Xlds[4][64][40];    // per-wave X chunk, 80B rows
    __shared__ __align__(16) ushort_t Hlds[4][64][40];    // per-wave [h | 1 | 0] chunk
    __shared__ __align__(16) float    Sdls[4][64];        // per-wave sd broadcast

    int tid = threadIdx.x;
    int w = tid >> 6, l = tid & 63;
    int lc = l & 15, lg = l >> 4;
    int l31 = l & 31;
    bool hi32 = (l >= 32);
    int ray = blockIdx.x * 256 + tid;
    int BN = B * N;
    int b = ray / N;

    // stage gate-weight fragments into LDS
    {
        const uintx4* src = (const uintx4*)ws;
        uintx4* dst = (uintx4*)Blds;
        for (int i = tid; i < GPACK_N / 8; i += 256) dst[i] = src[i];
    }

    // load phi A-fragments (loop-invariant, 32 VGPRs)
    short8 phiA[8];
    {
        const short8* pA = (const short8*)((const char*)ws + WS_PHIA_B);
#pragma unroll
        for (int ft = 0; ft < 8; ++ft) phiA[ft] = pA[ft * 64 + l];
    }

    const float* M = c2w + b * 16;
    float R00 = M[0], R01 = M[1], R02 = M[2], t0 = M[3];
    float R10 = M[4], R11 = M[5], R12 = M[6], t1 = M[7];
    float R20 = M[8], R21 = M[9], R22 = M[10], t2 = M[11];
    const float* Kc = intr + b * 9;
    float fx = Kc[0], cx = Kc[2], fy = Kc[4], cy = Kc[5];

    float u = uv[ray * 2 + 0];
    float v = uv[ray * 2 + 1];
    float d0 = dep0[ray];

    float xl = (u - cx) / fx;
    float yl = (v - cy) / fy;
    float dx = R00 * xl + R01 * yl + R02;
    float dy = R10 * xl + R11 * yl + R12;
    float dz = R20 * xl + R21 * yl + R22;
    float invn = rsqrtf(dx * dx + dy * dy + dz * dz);
    float rdx = dx * invn, rdy = dy * invn, rdz = dz * invn;
    float w0 = fmaf(dx, d0, t0);
    float w1 = fmaf(dy, d0, t1);
    float w2 = fmaf(dz, d0, t2);

    // init Hlds row: shorts 0-15 = h = 0, short 16 = bf16(1.0), 17-31 = 0
    {
        uintx4 z4 = {0u, 0u, 0u, 0u};
        uintx4 o4 = {0x00003F80u, 0u, 0u, 0u};
        uintx4* hr = (uintx4*)&Hlds[w][l][0];
        hr[0] = z4; hr[1] = z4; hr[2] = o4; hr[3] = z4;
    }

    float wj = Wout[lc];
    float bo = bout[0];

    float h[HID], c[HID];
#pragma unroll
    for (int j = 0; j < HID; ++j) { h[j] = 0.f; c[j] = 0.f; }

    __syncthreads();  // Blds staged

#pragma unroll 1
    for (int s = 0; s < STEPS; ++s) {
        // ---- build world B-fragments (32x32x16): lane holds k=(l>>5)*8+e of ray rt*32+(l&31)
        // rt0: own w; rt1: partner half via shfl. lanes>=32 are k=8..15 -> zero.
        float s0 = __shfl(w0, l31 + 32);
        float s1 = __shfl(w1, l31 + 32);
        float s2 = __shfl(w2, l31 + 32);
        short8 bw0, bw1;
        {
            unsigned a0 = hi32 ? 0u : packhl(w0);
            unsigned a1 = hi32 ? 0u : packhl(w1);
            unsigned a2 = hi32 ? 0u : packhl(w2);
            unsigned a3 = hi32 ? 0u : 0x00003F80u;
            unsigned c0 = hi32 ? 0u : packhl(s0);
            unsigned c1 = hi32 ? 0u : packhl(s1);
            unsigned c2 = hi32 ? 0u : packhl(s2);
            union { unsigned u[4]; short8 s; } cv0, cv1;
            cv0.u[0] = a0; cv0.u[1] = a1; cv0.u[2] = a2; cv0.u[3] = a3;
            cv1.u[0] = c0; cv1.u[1] = c1; cv1.u[2] = c2; cv1.u[3] = a3;
            bw0 = cv0.s; bw1 = cv1.s;
        }

        floatx4 acc[4][4];
#pragma unroll
        for (int m = 0; m < 4; ++m)
#pragma unroll
            for (int n = 0; n < 4; ++n) acc[m][n] = (floatx4){0.f, 0.f, 0.f, 0.f};

        // ---- 8 feature chunks: phi via MFMA -> relu/pack -> LDS -> gates MFMA
#pragma unroll
        for (int kc = 0; kc < 8; ++kc) {
            floatx16 zz = (floatx16){0.f,0.f,0.f,0.f,0.f,0.f,0.f,0.f,
                                     0.f,0.f,0.f,0.f,0.f,0.f,0.f,0.f};
            floatx16 p0 = __builtin_amdgcn_mfma_f32_32x32x16_bf16(phiA[kc], bw0, zz, 0, 0, 0);
            floatx16 p1 = __builtin_amdgcn_mfma_f32_32x32x16_bf16(phiA[kc], bw1, zz, 0, 0, 0);
            // C/D: col(ray)=l&31, row(local feat)=(reg&3)+8*(reg>>2)+4*hi32
            // reg pairs (2q,2q+1) are consecutive feats; b64 groups -> feats {0,8,16,24}+4*hi32
            {
                uint2v* q0 = (uint2v*)&Xlds[w][l31][4 * (int)hi32];
                uint2v d;
                d.x = relupk(p0[0],  p0[1]);  d.y = relupk(p0[2],  p0[3]);  q0[0] = d;
                d.x = relupk(p0[4],  p0[5]);  d.y = relupk(p0[6],  p0[7]);  q0[2] = d;
                d.x = relupk(p0[8],  p0[9]);  d.y = relupk(p0[10], p0[11]); q0[4] = d;
                d.x = relupk(p0[12], p0[13]); d.y = relupk(p0[14], p0[15]); q0[6] = d;
                uint2v* q1 = (uint2v*)&Xlds[w][32 + l31][4 * (int)hi32];
                d.x = relupk(p1[0],  p1[1]);  d.y = relupk(p1[2],  p1[3]);  q1[0] = d;
                d.x = relupk(p1[4],  p1[5]);  d.y = relupk(p1[6],  p1[7]);  q1[2] = d;
                d.x = relupk(p1[8],  p1[9]);  d.y = relupk(p1[10], p1[11]); q1[4] = d;
                d.x = relupk(p1[12], p1[13]); d.y = relupk(p1[14], p1[15]); q1[6] = d;
            }
            // gates: A = X (rays x K), B = weights
            short8 af[4], bf[4];
#pragma unroll
            for (int m = 0; m < 4; ++m)
                af[m] = *(const short8*)&Xlds[w][16 * m + lc][lg * 8];
#pragma unroll
            for (int n = 0; n < 4; ++n)
                bf[n] = *(const short8*)&Blds[((kc * 4 + n) * 64 + l) * 8];
#pragma unroll
            for (int m = 0; m < 4; ++m)
#pragma unroll
                for (int n = 0; n < 4; ++n)
                    acc[m][n] = __builtin_amdgcn_mfma_f32_16x16x32_bf16(
                        af[m], bf[n], acc[m][n], 0, 0, 0);
        }

        // ---- chunk 8: [h | 1 | 0] @ [Whh^T; bias; 0]
        {
            short8 af[4], bf[4];
#pragma unroll
            for (int m = 0; m < 4; ++m)
                af[m] = *(const short8*)&Hlds[w][16 * m + lc][lg * 8];
#pragma unroll
            for (int n = 0; n < 4; ++n)
                bf[n] = *(const short8*)&Blds[((8 * 4 + n) * 64 + l) * 8];
#pragma unroll
            for (int m = 0; m < 4; ++m)
#pragma unroll
                for (int n = 0; n < 4; ++n)
                    acc[m][n] = __builtin_amdgcn_mfma_f32_16x16x32_bf16(
                        af[m], bf[n], acc[m][n], 0, 0, 0);
        }

        // ---- LSTM (gates pre-scaled by log2e; g-col by 2log2e) ----
        const float L2 = 2.8853900817779268f;  // 2*log2(e)
        float sp[4][4];
#pragma unroll
        for (int m = 0; m < 4; ++m) {
#pragma unroll
            for (int i = 0; i < 4; ++i) {
                float ig = __builtin_amdgcn_rcpf(1.f + __builtin_amdgcn_exp2f(-acc[m][0][i]));
                float fg = __builtin_amdgcn_rcpf(1.f + __builtin_amdgcn_exp2f(-acc[m][1][i]));
                float gg = fmaf(-2.f, __builtin_amdgcn_rcpf(1.f + __builtin_amdgcn_exp2f(acc[m][2][i])), 1.f);
                float og = __builtin_amdgcn_rcpf(1.f + __builtin_amdgcn_exp2f(-acc[m][3][i]));
                int idx = m * 4 + i;
                float cn = fmaf(fg, c[idx], ig * gg);
                c[idx] = cn;
                float tc = fmaf(-2.f, __builtin_amdgcn_rcpf(1.f + __builtin_amdgcn_exp2f(L2 * cn)), 1.f);
                float hn = og * tc;
                h[idx] = hn;
                sp[m][i] = hn * wj;
            }
        }
        // reduce sd over the 16 lanes (hidden dims) sharing the same rays
#pragma unroll
        for (int r = 1; r < 16; r <<= 1) {
#pragma unroll
            for (int m = 0; m < 4; ++m)
#pragma unroll
                for (int i = 0; i < 4; ++i)
                    sp[m][i] += __shfl_xor(sp[m][i], r, 64);
        }
        if (lc == 0) {
#pragma unroll
            for (int m = 0; m < 4; ++m) {
                floatx4 vv = {sp[m][0], sp[m][1], sp[m][2], sp[m][3]};
                *(floatx4*)&Sdls[w][16 * m + 4 * lg] = vv;
            }
        }
        // write h (bf16) into Hlds for next step's chunk 8
#pragma unroll
        for (int m = 0; m < 4; ++m)
#pragma unroll
            for (int i = 0; i < 4; ++i) {
                unsigned hb = pk2bf(h[m * 4 + i], h[m * 4 + i]);
                Hlds[w][16 * m + 4 * lg + i][lc] = (ushort_t)hb;
            }

        float sdv = Sdls[w][l] + bo;
        w0 = fmaf(rdx, sdv, w0);
        w1 = fmaf(rdy, sdv, w1);
        w2 = fmaf(rdz, sdv, w2);
    }

    int base = ray * 3;
    out[base + 0] = w0;
    out[base + 1] = w1;
    out[base + 2] = w2;
    float dd = R02 * (w0 - t0) + R12 * (w1 - t1) + R22 * (w2 - t2);
    out[BN * 3 + ray] = dd;
}

extern "C" void kernel_launch(void* const* d_in, const int* in_sizes, int n_in,
                              void* d_out, int out_size, void* d_ws, size_t ws_size,
                              hipStream_t stream) {
    const float* c2w  = (const float*)d_in[0];
    const float* intr = (const float*)d_in[1];
    const float* uv   = (const float*)d_in[2];
    const float* dep  = (const float*)d_in[3];
    const float* Wphi = (const float*)d_in[4];
    const float* bphi = (const float*)d_in[5];
    const float* Wih  = (const float*)d_in[6];
    const float* bih  = (const float*)d_in[7];
    const float* Whh  = (const float*)d_in[8];
    const float* bhh  = (const float*)d_in[9];
    const float* Wout = (const float*)d_in[10];
    const float* bout = (const float*)d_in[11];
    float* out = (float*)d_out;

    int B = in_sizes[0] / 16;
    int BN = in_sizes[3];
    int N = BN / B;
    int blocks = (BN + 255) / 256;

    int prep_items = GPACK_N + PHIA_N;
    prep<<<(prep_items + 255) / 256, 256, 0, stream>>>(Wphi, bphi, Wih, bih, Whh, bhh, d_ws);
    march<<<blocks, 256, 0, stream>>>(c2w, intr, uv, dep, d_ws, Wout, bout, out, B, N);
}